// Round 4
// baseline (573.766 us; speedup 1.0000x reference)
//
#include <hip/hip_runtime.h>
#include <hip/hip_bf16.h>

constexpr int LAYERS = 24;
constexpr int DIM    = 2048;
constexpr int NBLK   = 8;
constexpr int BSZ    = 3;            // 24/8, remainder 0
constexpr float EPSV = 1e-6f;
constexpr int TPB    = 256;
constexpr int EPT    = 8;            // elements per thread
constexpr int HALF   = 1024;

typedef float vf4 __attribute__((ext_vector_type(4)));

// element j (0..7) of thread t lives at global d-index: (j>>2)*HALF + 4*t + (j&3)
// -> every 16B access is lane-contiguous (perfect 1KB/wave coalescing)

__device__ __forceinline__ unsigned pk2(float a, float b) {
    __hip_bfloat162 h2(__float2bfloat16(a), __float2bfloat16(b));
    union { __hip_bfloat162 h; unsigned u; } c; c.h = h2; return c.u;
}
__device__ __forceinline__ float upk(unsigned p, int hi) {
    union { unsigned u; float f; } c;
    c.u = hi ? (p & 0xffff0000u) : (p << 16);
    return c.f;
}

__global__ void prep_qw_kernel(const float* __restrict__ q,
                               const float* __restrict__ w,
                               float* __restrict__ qw, int n) {
    int idx = blockIdx.x * blockDim.x + threadIdx.x;
    if (idx < n) qw[idx] = q[idx] * w[idx & (DIM - 1)];
}

template<bool PREMUL>
__global__ void __launch_bounds__(TPB, 4)
block_attn_res_kernel(const float* __restrict__ lo,   // (L, B*T, D)
                      const float* __restrict__ emb,  // (B*T, D)
                      const float* __restrict__ q1,   // premultiplied q*w (L,D) or raw q
                      const float* __restrict__ wgt,  // (D) -- only if !PREMUL
                      float* __restrict__ out,        // (L, B*T, D)
                      int bt_total)
{
    const int bt   = blockIdx.x;
    const int tid  = threadIdx.x;
    const int lane = tid & 63;
    const int wid  = tid >> 6;
    const int c0   = tid * 4;

    __shared__ float red[2][4][12];

    // ---- embedding slice (f32, registers for whole kernel)
    float e[EPT];
    {
        const float* ep = emb + (size_t)bt * DIM;
        vf4 v0 = __builtin_nontemporal_load(reinterpret_cast<const vf4*>(ep + c0));
        vf4 v1 = __builtin_nontemporal_load(reinterpret_cast<const vf4*>(ep + HALF + c0));
        e[0]=v0.x; e[1]=v0.y; e[2]=v0.z; e[3]=v0.w;
        e[4]=v1.x; e[5]=v1.y; e[6]=v1.z; e[7]=v1.w;
    }

    unsigned Spk[NBLK-1][EPT/2];   // finished block sums, packed bf16x2
    float part[EPT];               // running within-block partial (f32)
    float ssq_S[NBLK-1];
    float ssq_emb;

    // ---- sumsq(emb) once (uses red[0]; safe: red[0] next written at layer 2,
    //      which is after layer 1's barrier)
    {
        float v = 0.f;
        #pragma unroll
        for (int j = 0; j < EPT; ++j) v += e[j] * e[j];
        #pragma unroll
        for (int off = 32; off; off >>= 1) v += __shfl_xor(v, off);
        if (lane == 0) red[0][wid][0] = v;
        __syncthreads();
        ssq_emb = red[0][0][0] + red[0][1][0] + red[0][2][0] + red[0][3][0];
    }
    const float invD = 1.f / (float)DIM;

    #pragma unroll
    for (int l = 0; l < LAYERS; ++l) {
        const int m    = l / BSZ;
        const int i    = l - m * BSZ;
        const int nsrc = 1 + m + (i > 0 ? 1 : 0);

        // ---- f_l slice (streamed, read-once; l=23's f feeds nothing -> skip)
        float f[EPT];
        if (l < LAYERS - 1) {
            const float* fp = lo + ((size_t)l * bt_total + bt) * DIM;
            vf4 u0 = __builtin_nontemporal_load(reinterpret_cast<const vf4*>(fp + c0));
            vf4 u1 = __builtin_nontemporal_load(reinterpret_cast<const vf4*>(fp + HALF + c0));
            f[0]=u0.x; f[1]=u0.y; f[2]=u0.z; f[3]=u0.w;
            f[4]=u1.x; f[5]=u1.y; f[6]=u1.z; f[7]=u1.w;
        } else {
            #pragma unroll
            for (int j = 0; j < EPT; ++j) f[j] = 0.f;
        }

        if (l == 0) {
            // single source -> softmax == 1 -> h = emb
            float* op = out + ((size_t)l * bt_total + bt) * DIM;
            vf4 w0; w0.x=e[0]; w0.y=e[1]; w0.z=e[2]; w0.w=e[3];
            vf4 w1; w1.x=e[4]; w1.y=e[5]; w1.z=e[6]; w1.w=e[7];
            *reinterpret_cast<vf4*>(op + c0) = w0;
            *reinterpret_cast<vf4*>(op + HALF + c0) = w1;
            #pragma unroll
            for (int j = 0; j < EPT; ++j) part[j] = f[j];
            continue;
        }

        // ---- q_l * w slice
        float qwv[EPT];
        {
            const float* qp = q1 + (size_t)l * DIM;
            vf4 v0 = *reinterpret_cast<const vf4*>(qp + c0);
            vf4 v1 = *reinterpret_cast<const vf4*>(qp + HALF + c0);
            qwv[0]=v0.x; qwv[1]=v0.y; qwv[2]=v0.z; qwv[3]=v0.w;
            qwv[4]=v1.x; qwv[5]=v1.y; qwv[6]=v1.z; qwv[7]=v1.w;
            if (!PREMUL) {
                vf4 w0 = *reinterpret_cast<const vf4*>(wgt + c0);
                vf4 w1 = *reinterpret_cast<const vf4*>(wgt + HALF + c0);
                qwv[0]*=w0.x; qwv[1]*=w0.y; qwv[2]*=w0.z; qwv[3]*=w0.w;
                qwv[4]*=w1.x; qwv[5]*=w1.y; qwv[6]*=w1.z; qwv[7]*=w1.w;
            }
        }

        // ---- per-thread partial dots (+ the one changing sumsq)
        float vals[11];
        int nv = 0;
        {
            float dv = 0.f;
            #pragma unroll
            for (int j = 0; j < EPT; ++j) dv += e[j] * qwv[j];
            vals[nv++] = dv;
        }
        #pragma unroll
        for (int s = 0; s < m; ++s) {
            float dv = 0.f;
            #pragma unroll
            for (int j = 0; j < EPT; ++j) dv += upk(Spk[s][j >> 1], j & 1) * qwv[j];
            vals[nv++] = dv;
        }
        if (i > 0) {
            float dv = 0.f, sq = 0.f;
            #pragma unroll
            for (int j = 0; j < EPT; ++j) { dv += part[j] * qwv[j]; sq += part[j] * part[j]; }
            vals[nv++] = dv;
            vals[nv++] = sq;
        } else {            // i==0, m>=1: finalize sumsq of S_{m-1} (bf16-consistent)
            float sq = 0.f;
            #pragma unroll
            for (int j = 0; j < EPT; ++j) {
                float sv = upk(Spk[m-1][j >> 1], j & 1);
                sq += sv * sv;
            }
            vals[nv++] = sq;
        }

        // ---- block reduction: wave shfl tree + 4-wave LDS join, ONE barrier
        const int p = l & 1;
        #pragma unroll
        for (int v = 0; v < nv; ++v) {
            float x = vals[v];
            #pragma unroll
            for (int off = 32; off; off >>= 1) x += __shfl_xor(x, off);
            if (lane == 0) red[p][wid][v] = x;
        }
        __syncthreads();
        #pragma unroll
        for (int v = 0; v < nv; ++v)
            vals[v] = red[p][0][v] + red[p][1][v] + red[p][2][v] + red[p][3][v];
        // (no trailing barrier: red[p] is next overwritten two layers later,
        //  strictly after the intervening layer's barrier)

        if (i == 0) ssq_S[m-1] = vals[nsrc];
        const float ssq_part = (i > 0) ? vals[nsrc] : 0.f;

        // ---- scores
        float scr[NBLK + 1];
        scr[0] = vals[0] * rsqrtf(ssq_emb * invD + EPSV);
        #pragma unroll
        for (int s = 0; s < m; ++s)
            scr[1+s] = vals[1+s] * rsqrtf(ssq_S[s] * invD + EPSV);
        if (i > 0)
            scr[m+1] = vals[m+1] * rsqrtf(ssq_part * invD + EPSV);

        // ---- softmax over nsrc (<=9, replicated)
        float mx = scr[0];
        #pragma unroll
        for (int s = 1; s < nsrc; ++s) mx = fmaxf(mx, scr[s]);
        float al[NBLK + 1];
        float den = 0.f;
        #pragma unroll
        for (int s = 0; s < nsrc; ++s) { al[s] = __expf(scr[s] - mx); den += al[s]; }
        const float inv = 1.f / den;

        // ---- h = sum_s alpha_s * v_s
        float h[EPT];
        {
            const float a = al[0] * inv;
            #pragma unroll
            for (int j = 0; j < EPT; ++j) h[j] = a * e[j];
        }
        #pragma unroll
        for (int s = 0; s < m; ++s) {
            const float a = al[1+s] * inv;
            #pragma unroll
            for (int j = 0; j < EPT; ++j) h[j] += a * upk(Spk[s][j >> 1], j & 1);
        }
        if (i > 0) {
            const float a = al[m+1] * inv;
            #pragma unroll
            for (int j = 0; j < EPT; ++j) h[j] += a * part[j];
        }

        // ---- store (temporal: full-line write-back coalescing in L2)
        {
            float* op = out + ((size_t)l * bt_total + bt) * DIM;
            vf4 w0; w0.x=h[0]; w0.y=h[1]; w0.z=h[2]; w0.w=h[3];
            vf4 w1; w1.x=h[4]; w1.y=h[5]; w1.z=h[6]; w1.w=h[7];
            *reinterpret_cast<vf4*>(op + c0) = w0;
            *reinterpret_cast<vf4*>(op + HALF + c0) = w1;
        }

        // ---- advance partial / finalize block sum (packed bf16)
        if (l < LAYERS - 1) {
            if (i == 0) {
                #pragma unroll
                for (int j = 0; j < EPT; ++j) part[j] = f[j];
            } else {
                #pragma unroll
                for (int j = 0; j < EPT; ++j) part[j] += f[j];
            }
            if (i == BSZ - 1 && m < NBLK - 1) {
                #pragma unroll
                for (int j2 = 0; j2 < EPT/2; ++j2)
                    Spk[m][j2] = pk2(part[2*j2], part[2*j2 + 1]);
            }
        }
    }
}

extern "C" void kernel_launch(void* const* d_in, const int* in_sizes, int n_in,
                              void* d_out, int out_size, void* d_ws, size_t ws_size,
                              hipStream_t stream) {
    const float* lo  = (const float*)d_in[0];  // layer_outputs (L,B,T,D)
    const float* emb = (const float*)d_in[1];  // embedding (B,T,D)
    const float* qry = (const float*)d_in[2];  // queries (L,D)
    const float* wgt = (const float*)d_in[3];  // key_norm_weight (D)
    float* outp = (float*)d_out;

    const int bt_total = in_sizes[1] / DIM;    // B*T
    const int nq = in_sizes[2];                // L*D

    if (ws_size >= (size_t)nq * sizeof(float)) {
        float* qwbuf = (float*)d_ws;
        prep_qw_kernel<<<(nq + TPB - 1) / TPB, TPB, 0, stream>>>(qry, wgt, qwbuf, nq);
        block_attn_res_kernel<true><<<bt_total, TPB, 0, stream>>>(
            lo, emb, qwbuf, nullptr, outp, bt_total);
    } else {
        block_attn_res_kernel<false><<<bt_total, TPB, 0, stream>>>(
            lo, emb, qry, wgt, outp, bt_total);
    }
}

// Round 5
// 461.413 us; speedup vs baseline: 1.2435x; 1.2435x over previous
//
#include <hip/hip_runtime.h>
#include <hip/hip_bf16.h>

constexpr int LAYERS = 24;
constexpr int DIM    = 2048;
constexpr int NBLK   = 8;
constexpr int BSZ    = 3;            // 24/8, remainder 0
constexpr float EPSV = 1e-6f;
constexpr int TPB    = 512;
constexpr int EPT    = 4;            // one float4 slice per thread
constexpr int NWAVE  = TPB / 64;

typedef float vf4 __attribute__((ext_vector_type(4)));

__device__ __forceinline__ unsigned pk2(float a, float b) {
    __hip_bfloat162 h2(__float2bfloat16(a), __float2bfloat16(b));
    union { __hip_bfloat162 h; unsigned u; } c; c.h = h2; return c.u;
}
__device__ __forceinline__ float upk(unsigned p, int hi) {
    union { unsigned u; float f; } c;
    c.u = hi ? (p & 0xffff0000u) : (p << 16);
    return c.f;
}

__global__ void prep_qw_kernel(const float* __restrict__ q,
                               const float* __restrict__ w,
                               float* __restrict__ qw, int n) {
    int idx = blockIdx.x * blockDim.x + threadIdx.x;
    if (idx < n) qw[idx] = q[idx] * w[idx & (DIM - 1)];
}

template<bool PREMUL>
__global__ void __launch_bounds__(TPB, 4)   // cap 128 unified regs; demand ~70 -> no scratch
block_attn_res_kernel(const float* __restrict__ lo,   // (L, B*T, D)
                      const float* __restrict__ emb,  // (B*T, D)
                      const float* __restrict__ q1,   // premultiplied q*w (L,D) or raw q
                      const float* __restrict__ wgt,  // (D) -- only if !PREMUL
                      float* __restrict__ out,        // (L, B*T, D)
                      int bt_total)
{
    const int bt   = blockIdx.x;
    const int tid  = threadIdx.x;
    const int lane = tid & 63;
    const int wid  = tid >> 6;
    const int c0   = tid * 4;            // thread owns d-indices [4t, 4t+4)

    __shared__ float red[2][NWAVE][12];

    // ---- embedding slice (registers for whole kernel)
    float e[EPT];
    {
        vf4 v0 = __builtin_nontemporal_load(
            reinterpret_cast<const vf4*>(emb + (size_t)bt * DIM + c0));
        e[0]=v0.x; e[1]=v0.y; e[2]=v0.z; e[3]=v0.w;
    }

    unsigned Spk[NBLK-1][EPT/2];   // finished block sums, packed bf16x2 (14 regs)
    float part[EPT];               // running within-block partial (f32)
    float ssq_S[NBLK-1];
    float ssq_emb;

    // ---- sumsq(emb) once
    {
        float v = 0.f;
        #pragma unroll
        for (int j = 0; j < EPT; ++j) v += e[j] * e[j];
        #pragma unroll
        for (int off = 32; off; off >>= 1) v += __shfl_xor(v, off);
        if (lane == 0) red[0][wid][0] = v;
        __syncthreads();
        float s = 0.f;
        #pragma unroll
        for (int w = 0; w < NWAVE; ++w) s += red[0][w][0];
        ssq_emb = s;
    }
    const float invD = 1.f / (float)DIM;

    #pragma unroll
    for (int l = 0; l < LAYERS; ++l) {
        const int m    = l / BSZ;
        const int i    = l - m * BSZ;
        const int nsrc = 1 + m + (i > 0 ? 1 : 0);

        // ---- f_l slice (streamed; l=23's f feeds nothing -> skip)
        float f[EPT];
        if (l < LAYERS - 1) {
            vf4 u0 = __builtin_nontemporal_load(
                reinterpret_cast<const vf4*>(lo + ((size_t)l * bt_total + bt) * DIM + c0));
            f[0]=u0.x; f[1]=u0.y; f[2]=u0.z; f[3]=u0.w;
        } else {
            #pragma unroll
            for (int j = 0; j < EPT; ++j) f[j] = 0.f;
        }

        if (l == 0) {
            // single source -> softmax == 1 -> h = emb
            vf4 w0; w0.x=e[0]; w0.y=e[1]; w0.z=e[2]; w0.w=e[3];
            *reinterpret_cast<vf4*>(out + ((size_t)l * bt_total + bt) * DIM + c0) = w0;
            #pragma unroll
            for (int j = 0; j < EPT; ++j) part[j] = f[j];
            continue;
        }

        // ---- q_l * w slice
        float qwv[EPT];
        {
            vf4 v0 = *reinterpret_cast<const vf4*>(q1 + (size_t)l * DIM + c0);
            qwv[0]=v0.x; qwv[1]=v0.y; qwv[2]=v0.z; qwv[3]=v0.w;
            if (!PREMUL) {
                vf4 w0 = *reinterpret_cast<const vf4*>(wgt + c0);
                qwv[0]*=w0.x; qwv[1]*=w0.y; qwv[2]*=w0.z; qwv[3]*=w0.w;
            }
        }

        // ---- per-thread partial dots (+ the one changing sumsq)
        float vals[11];
        int nv = 0;
        {
            float dv = 0.f;
            #pragma unroll
            for (int j = 0; j < EPT; ++j) dv += e[j] * qwv[j];
            vals[nv++] = dv;
        }
        #pragma unroll
        for (int s = 0; s < m; ++s) {
            float dv = 0.f;
            #pragma unroll
            for (int j = 0; j < EPT; ++j) dv += upk(Spk[s][j >> 1], j & 1) * qwv[j];
            vals[nv++] = dv;
        }
        if (i > 0) {
            float dv = 0.f, sq = 0.f;
            #pragma unroll
            for (int j = 0; j < EPT; ++j) { dv += part[j] * qwv[j]; sq += part[j] * part[j]; }
            vals[nv++] = dv;
            vals[nv++] = sq;
        } else {            // i==0, m>=1: finalize sumsq of S_{m-1} (bf16-consistent)
            float sq = 0.f;
            #pragma unroll
            for (int j = 0; j < EPT; ++j) {
                float sv = upk(Spk[m-1][j >> 1], j & 1);
                sq += sv * sv;
            }
            vals[nv++] = sq;
        }

        // ---- block reduction: wave shfl tree + NWAVE LDS join, ONE barrier
        const int p = l & 1;
        #pragma unroll
        for (int v = 0; v < nv; ++v) {
            float x = vals[v];
            #pragma unroll
            for (int off = 32; off; off >>= 1) x += __shfl_xor(x, off);
            if (lane == 0) red[p][wid][v] = x;
        }
        __syncthreads();
        #pragma unroll
        for (int v = 0; v < nv; ++v) {
            float s = 0.f;
            #pragma unroll
            for (int w = 0; w < NWAVE; ++w) s += red[p][w][v];
            vals[v] = s;
        }
        // (no trailing barrier: red[p] is next overwritten two layers later,
        //  strictly after the intervening layer's barrier)

        if (i == 0) ssq_S[m-1] = vals[nsrc];
        const float ssq_part = (i > 0) ? vals[nsrc] : 0.f;

        // ---- scores
        float scr[NBLK + 1];
        scr[0] = vals[0] * rsqrtf(ssq_emb * invD + EPSV);
        #pragma unroll
        for (int s = 0; s < m; ++s)
            scr[1+s] = vals[1+s] * rsqrtf(ssq_S[s] * invD + EPSV);
        if (i > 0)
            scr[m+1] = vals[m+1] * rsqrtf(ssq_part * invD + EPSV);

        // ---- softmax over nsrc (<=9, replicated)
        float mx = scr[0];
        #pragma unroll
        for (int s = 1; s < nsrc; ++s) mx = fmaxf(mx, scr[s]);
        float al[NBLK + 1];
        float den = 0.f;
        #pragma unroll
        for (int s = 0; s < nsrc; ++s) { al[s] = __expf(scr[s] - mx); den += al[s]; }
        const float inv = 1.f / den;

        // ---- h = sum_s alpha_s * v_s
        float h[EPT];
        {
            const float a = al[0] * inv;
            #pragma unroll
            for (int j = 0; j < EPT; ++j) h[j] = a * e[j];
        }
        #pragma unroll
        for (int s = 0; s < m; ++s) {
            const float a = al[1+s] * inv;
            #pragma unroll
            for (int j = 0; j < EPT; ++j) h[j] += a * upk(Spk[s][j >> 1], j & 1);
        }
        if (i > 0) {
            const float a = al[m+1] * inv;
            #pragma unroll
            for (int j = 0; j < EPT; ++j) h[j] += a * part[j];
        }

        // ---- store (temporal, lane-contiguous 1KB/wave)
        {
            vf4 w0; w0.x=h[0]; w0.y=h[1]; w0.z=h[2]; w0.w=h[3];
            *reinterpret_cast<vf4*>(out + ((size_t)l * bt_total + bt) * DIM + c0) = w0;
        }

        // ---- advance partial / finalize block sum (packed bf16)
        if (l < LAYERS - 1) {
            if (i == 0) {
                #pragma unroll
                for (int j = 0; j < EPT; ++j) part[j] = f[j];
            } else {
                #pragma unroll
                for (int j = 0; j < EPT; ++j) part[j] += f[j];
            }
            if (i == BSZ - 1 && m < NBLK - 1) {
                #pragma unroll
                for (int j2 = 0; j2 < EPT/2; ++j2)
                    Spk[m][j2] = pk2(part[2*j2], part[2*j2 + 1]);
            }
        }
    }
}

extern "C" void kernel_launch(void* const* d_in, const int* in_sizes, int n_in,
                              void* d_out, int out_size, void* d_ws, size_t ws_size,
                              hipStream_t stream) {
    const float* lo  = (const float*)d_in[0];  // layer_outputs (L,B,T,D)
    const float* emb = (const float*)d_in[1];  // embedding (B,T,D)
    const float* qry = (const float*)d_in[2];  // queries (L,D)
    const float* wgt = (const float*)d_in[3];  // key_norm_weight (D)
    float* outp = (float*)d_out;

    const int bt_total = in_sizes[1] / DIM;    // B*T
    const int nq = in_sizes[2];                // L*D

    if (ws_size >= (size_t)nq * sizeof(float)) {
        float* qwbuf = (float*)d_ws;
        prep_qw_kernel<<<(nq + 255) / 256, 256, 0, stream>>>(qry, wgt, qwbuf, nq);
        block_attn_res_kernel<true><<<bt_total, TPB, 0, stream>>>(
            lo, emb, qwbuf, nullptr, outp, bt_total);
    } else {
        block_attn_res_kernel<false><<<bt_total, TPB, 0, stream>>>(
            lo, emb, qry, wgt, outp, bt_total);
    }
}

// Round 6
// 222.461 us; speedup vs baseline: 2.5792x; 2.0741x over previous
//
#include <hip/hip_runtime.h>
#include <hip/hip_bf16.h>

constexpr int LAYERS = 24;
constexpr int DIM    = 2048;
constexpr int NBLK   = 8;
constexpr float EPSV = 1e-6f;
constexpr int TPB    = 512;
constexpr int EPT    = 4;            // one float4 slice per thread
constexpr int NSLOT  = 147;          // total block-wide reduced scalars

typedef float vf4 __attribute__((ext_vector_type(4)));

// Reduced-value layout (slot indices):
//   slot 0: ssq(emb)
//   layer l (1..23), m=l/3, i=l%3, off=OFF_TAB[l]:
//     off+0        : dot(emb, qw_l)
//     off+1+s      : dot(S_s, qw_l)          s = 0..m-1
//     i>0:  off+m+1: dot(part_l, qw_l),  off+m+2: ssq(part_l)
//     i==0: off+m+1: ssq(S_{m-1})  (computed from f32 part before overwrite)
__device__ constexpr int OFF_TAB[24] =
    {0,1,4,7,10,14,18,22,27,32,37,43,49,55,62,69,76,84,92,100,109,118,127,137};
__device__ constexpr int SSQS[7] = {9,21,36,54,75,99,126};  // ssq(S_s) slots

__device__ __forceinline__ unsigned pk2(float a, float b) {
    __hip_bfloat162 h2(__float2bfloat16(a), __float2bfloat16(b));
    union { __hip_bfloat162 h; unsigned u; } c; c.h = h2; return c.u;
}
__device__ __forceinline__ float upk(unsigned p, int hi) {
    union { unsigned u; float f; } c;
    c.u = hi ? (p & 0xffff0000u) : (p << 16);
    return c.f;
}

__global__ void prep_qw_kernel(const float* __restrict__ q,
                               const float* __restrict__ w,
                               float* __restrict__ qw, int n) {
    int idx = blockIdx.x * blockDim.x + threadIdx.x;
    if (idx < n) qw[idx] = q[idx] * w[idx & (DIM - 1)];
}

template<bool PREMUL>
__global__ void __launch_bounds__(TPB, 4)   // cap 128 unified regs; demand ~100
block_attn_res_kernel(const float* __restrict__ lo,   // (L, B*T, D)
                      const float* __restrict__ emb,  // (B*T, D)
                      const float* __restrict__ q1,   // premultiplied q*w (L,D) or raw q
                      const float* __restrict__ wgt,  // (D) -- only if !PREMUL
                      float* __restrict__ out,        // (L, B*T, D)
                      int bt_total)
{
    const int bt   = blockIdx.x;
    const int tid  = threadIdx.x;
    const int lane = tid & 63;
    const int wid  = tid >> 6;
    const int grp  = (wid << 2) | (lane >> 4);   // 16-lane group id, 0..31
    const int c0   = tid * 4;                    // thread owns d-indices [4t,4t+4)

    __shared__ float red[32][NSLOT + 1];   // group partials
    __shared__ float redJ[NSLOT + 1];      // joined scalars
    __shared__ float ab[LAYERS][12];       // normalized alphas per layer

    const float invD = 1.f / (float)DIM;

    // 4-step (16-lane) wave reduce, group leader writes LDS
    auto wred = [&](float x, int slot) {
        x += __shfl_xor(x, 1);
        x += __shfl_xor(x, 2);
        x += __shfl_xor(x, 4);
        x += __shfl_xor(x, 8);
        if ((lane & 15) == 0) red[grp][slot] = x;
    };

    // ---- embedding slice (registers for whole kernel)
    float e[EPT];
    {
        vf4 v0 = __builtin_nontemporal_load(
            reinterpret_cast<const vf4*>(emb + (size_t)bt * DIM + c0));
        e[0]=v0.x; e[1]=v0.y; e[2]=v0.z; e[3]=v0.w;
    }

    unsigned fpk[LAYERS-1][EPT/2];   // f_0..f_22 packed bf16x2 (46 regs)
    unsigned Spk[NBLK-1][EPT/2];     // finished block sums S_0..S_6, bf16x2
    float part[EPT];                 // running within-block partial (f32)

    // ================= PHASE 1: stream, evolve, emit reduction partials ====
    // l = 0: out = emb (softmax over single source), seed part
    {
        vf4 u0 = __builtin_nontemporal_load(
            reinterpret_cast<const vf4*>(lo + (size_t)0 * bt_total * DIM
                                            + (size_t)bt * DIM + c0));
        part[0]=u0.x; part[1]=u0.y; part[2]=u0.z; part[3]=u0.w;
        fpk[0][0] = pk2(part[0], part[1]);
        fpk[0][1] = pk2(part[2], part[3]);

        vf4 w0; w0.x=e[0]; w0.y=e[1]; w0.z=e[2]; w0.w=e[3];
        *reinterpret_cast<vf4*>(out + (size_t)bt * DIM + c0) = w0;

        float sq = e[0]*e[0] + e[1]*e[1] + e[2]*e[2] + e[3]*e[3];
        wred(sq, 0);
    }

    #pragma unroll
    for (int l = 1; l < LAYERS; ++l) {
        const int m   = l / 3;
        const int i   = l - 3 * m;
        const int off = OFF_TAB[l];

        // f_l slice (f_23 is dead -> skip)
        float f[EPT];
        if (l < LAYERS - 1) {
            vf4 u0 = __builtin_nontemporal_load(
                reinterpret_cast<const vf4*>(lo + ((size_t)l * bt_total + bt) * DIM + c0));
            f[0]=u0.x; f[1]=u0.y; f[2]=u0.z; f[3]=u0.w;
        }

        // q_l * w slice
        float qwv[EPT];
        {
            vf4 v0 = *reinterpret_cast<const vf4*>(q1 + (size_t)l * DIM + c0);
            qwv[0]=v0.x; qwv[1]=v0.y; qwv[2]=v0.z; qwv[3]=v0.w;
            if (!PREMUL) {
                vf4 w0 = *reinterpret_cast<const vf4*>(wgt + c0);
                qwv[0]*=w0.x; qwv[1]*=w0.y; qwv[2]*=w0.z; qwv[3]*=w0.w;
            }
        }

        // dot(emb, qw)
        {
            float dv = e[0]*qwv[0] + e[1]*qwv[1] + e[2]*qwv[2] + e[3]*qwv[3];
            wred(dv, off);
        }
        // dot(S_s, qw); at i==0 the newest S (s=m-1) is still in f32 `part`
        #pragma unroll
        for (int s = 0; s < NBLK - 1; ++s) {
            if (s < m) {
                float dv;
                if (s == m - 1 && i == 0) {
                    dv = part[0]*qwv[0] + part[1]*qwv[1]
                       + part[2]*qwv[2] + part[3]*qwv[3];
                } else {
                    dv = upk(Spk[s][0],0)*qwv[0] + upk(Spk[s][0],1)*qwv[1]
                       + upk(Spk[s][1],0)*qwv[2] + upk(Spk[s][1],1)*qwv[3];
                }
                wred(dv, off + 1 + s);
            }
        }
        if (i > 0) {
            float dv = part[0]*qwv[0] + part[1]*qwv[1]
                     + part[2]*qwv[2] + part[3]*qwv[3];
            float sq = part[0]*part[0] + part[1]*part[1]
                     + part[2]*part[2] + part[3]*part[3];
            wred(dv, off + m + 1);
            wred(sq, off + m + 2);
        } else {
            // part still holds S_{m-1} in f32 here
            float sq = part[0]*part[0] + part[1]*part[1]
                     + part[2]*part[2] + part[3]*part[3];
            wred(sq, off + m + 1);
        }

        // advance partial / finalize block sum
        if (l < LAYERS - 1) {
            if (i == 0) {
                #pragma unroll
                for (int j = 0; j < EPT; ++j) part[j] = f[j];
            } else {
                #pragma unroll
                for (int j = 0; j < EPT; ++j) part[j] += f[j];
            }
            fpk[l][0] = pk2(f[0], f[1]);
            fpk[l][1] = pk2(f[2], f[3]);
            if (i == 2 && m < NBLK - 1) {
                Spk[m][0] = pk2(part[0], part[1]);
                Spk[m][1] = pk2(part[2], part[3]);
            }
        }
    }

    __syncthreads();   // barrier 1: all group partials in red[][]

    // ================= PHASE 2a: join 32 group partials per slot ===========
    if (tid < NSLOT) {
        float t = 0.f;
        #pragma unroll
        for (int g = 0; g < 32; ++g) t += red[g][tid];
        redJ[tid] = t;
    }
    __syncthreads();   // barrier 2: joined scalars ready

    // ================= PHASE 2b: per-layer scores + softmax (23 threads) ===
    if (tid >= 1 && tid < LAYERS) {
        const int l = tid;
        const int m = l / 3;
        const int i = l - 3 * m;
        const int off = OFF_TAB[l];
        const float ssqe = redJ[0];
        float sce = redJ[off] * rsqrtf(ssqe * invD + EPSV);
        float mx = sce;
        float scS[NBLK - 1];
        #pragma unroll
        for (int s = 0; s < NBLK - 1; ++s) {
            if (s < m) {
                scS[s] = redJ[off + 1 + s] * rsqrtf(redJ[SSQS[s]] * invD + EPSV);
                mx = fmaxf(mx, scS[s]);
            }
        }
        float scp = 0.f;
        if (i > 0) {
            scp = redJ[off + m + 1] * rsqrtf(redJ[off + m + 2] * invD + EPSV);
            mx = fmaxf(mx, scp);
        }
        float ee = __expf(sce - mx), den = ee;
        float es[NBLK - 1];
        #pragma unroll
        for (int s = 0; s < NBLK - 1; ++s) {
            es[s] = (s < m) ? __expf(scS[s] - mx) : 0.f;
            den += es[s];
        }
        float ep = 0.f;
        if (i > 0) { ep = __expf(scp - mx); den += ep; }
        const float inv = 1.f / den;
        ab[l][0] = ee * inv;
        #pragma unroll
        for (int s = 0; s < NBLK - 1; ++s)
            if (s < m) ab[l][1 + s] = es[s] * inv;
        if (i > 0) ab[l][1 + m] = ep * inv;
    }
    __syncthreads();   // barrier 3: alphas ready

    // ================= PHASE 3: emit outputs (no sync, pure FMA) ===========
    // re-evolve partial from bf16 f's
    part[0] = upk(fpk[0][0],0); part[1] = upk(fpk[0][0],1);
    part[2] = upk(fpk[0][1],0); part[3] = upk(fpk[0][1],1);

    #pragma unroll
    for (int l = 1; l < LAYERS; ++l) {
        const int m = l / 3;
        const int i = l - 3 * m;

        float h[EPT];
        {
            const float a0 = ab[l][0];
            #pragma unroll
            for (int j = 0; j < EPT; ++j) h[j] = a0 * e[j];
        }
        #pragma unroll
        for (int s = 0; s < NBLK - 1; ++s) {
            if (s < m) {
                const float a = ab[l][1 + s];
                h[0] += a * upk(Spk[s][0],0);
                h[1] += a * upk(Spk[s][0],1);
                h[2] += a * upk(Spk[s][1],0);
                h[3] += a * upk(Spk[s][1],1);
            }
        }
        if (i > 0) {
            const float a = ab[l][1 + m];
            #pragma unroll
            for (int j = 0; j < EPT; ++j) h[j] += a * part[j];
        }

        {
            vf4 w0; w0.x=h[0]; w0.y=h[1]; w0.z=h[2]; w0.w=h[3];
            *reinterpret_cast<vf4*>(out + ((size_t)l * bt_total + bt) * DIM + c0) = w0;
        }

        if (l < LAYERS - 1) {
            if (i == 0) {
                part[0] = upk(fpk[l][0],0); part[1] = upk(fpk[l][0],1);
                part[2] = upk(fpk[l][1],0); part[3] = upk(fpk[l][1],1);
            } else {
                part[0] += upk(fpk[l][0],0); part[1] += upk(fpk[l][0],1);
                part[2] += upk(fpk[l][1],0); part[3] += upk(fpk[l][1],1);
            }
        }
    }
}

extern "C" void kernel_launch(void* const* d_in, const int* in_sizes, int n_in,
                              void* d_out, int out_size, void* d_ws, size_t ws_size,
                              hipStream_t stream) {
    const float* lo  = (const float*)d_in[0];  // layer_outputs (L,B,T,D)
    const float* emb = (const float*)d_in[1];  // embedding (B,T,D)
    const float* qry = (const float*)d_in[2];  // queries (L,D)
    const float* wgt = (const float*)d_in[3];  // key_norm_weight (D)
    float* outp = (float*)d_out;

    const int bt_total = in_sizes[1] / DIM;    // B*T
    const int nq = in_sizes[2];                // L*D

    if (ws_size >= (size_t)nq * sizeof(float)) {
        float* qwbuf = (float*)d_ws;
        prep_qw_kernel<<<(nq + 255) / 256, 256, 0, stream>>>(qry, wgt, qwbuf, nq);
        block_attn_res_kernel<true><<<bt_total, TPB, 0, stream>>>(
            lo, emb, qwbuf, nullptr, outp, bt_total);
    } else {
        block_attn_res_kernel<false><<<bt_total, TPB, 0, stream>>>(
            lo, emb, qry, wgt, outp, bt_total);
    }
}

// Round 7
// 209.864 us; speedup vs baseline: 2.7340x; 1.0600x over previous
//
#include <hip/hip_runtime.h>
#include <hip/hip_bf16.h>

constexpr int LAYERS = 24;
constexpr int DIM    = 2048;
constexpr int NBLK   = 8;
constexpr float EPSV = 1e-6f;
constexpr int TPB    = 512;
constexpr int EPT    = 4;            // one float4 slice per thread
constexpr int NSLOT  = 147;          // total block-wide reduced scalars

typedef float vf4 __attribute__((ext_vector_type(4)));

// Reduced-value layout (slot indices):
//   slot 0: ssq(emb)
//   layer l (1..23), m=l/3, i=l%3, off=OFF_TAB[l]:
//     off+0        : dot(emb, qw_l)
//     off+1+s      : dot(S_s, qw_l)          s = 0..m-1
//     i>0:  off+m+1: dot(part_l, qw_l),  off+m+2: ssq(part_l)
//     i==0: off+m+1: ssq(S_{m-1})  (computed from f32 part before overwrite)
__device__ constexpr int OFF_TAB[24] =
    {0,1,4,7,10,14,18,22,27,32,37,43,49,55,62,69,76,84,92,100,109,118,127,137};
__device__ constexpr int SSQS[7] = {9,21,36,54,75,99,126};  // ssq(S_s) slots

__device__ __forceinline__ unsigned pk2(float a, float b) {
    __hip_bfloat162 h2(__float2bfloat16(a), __float2bfloat16(b));
    union { __hip_bfloat162 h; unsigned u; } c; c.h = h2; return c.u;
}
__device__ __forceinline__ float upk(unsigned p, int hi) {
    union { unsigned u; float f; } c;
    c.u = hi ? (p & 0xffff0000u) : (p << 16);
    return c.f;
}

__global__ void prep_qw_kernel(const float* __restrict__ q,
                               const float* __restrict__ w,
                               float* __restrict__ qw, int n) {
    int idx = blockIdx.x * blockDim.x + threadIdx.x;
    if (idx < n) qw[idx] = q[idx] * w[idx & (DIM - 1)];
}

template<bool PREMUL>
__global__ void __launch_bounds__(TPB, 4)   // cap 128 unified regs; demand ~80
block_attn_res_kernel(const float* __restrict__ lo,   // (L, B*T, D)
                      const float* __restrict__ emb,  // (B*T, D)
                      const float* __restrict__ q1,   // premultiplied q*w (L,D) or raw q
                      const float* __restrict__ wgt,  // (D) -- only if !PREMUL
                      float* __restrict__ out,        // (L, B*T, D)
                      int bt_total)
{
    const int bt   = blockIdx.x;
    const int tid  = threadIdx.x;
    const int lane = tid & 63;
    const int wid  = tid >> 6;
    const int grp  = (wid << 2) | (lane >> 4);   // 16-lane group id, 0..31
    const int c0   = tid * 4;                    // thread owns d-indices [4t,4t+4)

    __shared__ float red[32][NSLOT + 1];   // group partials
    __shared__ float redJ[NSLOT + 1];      // joined scalars
    __shared__ float ab[LAYERS][12];       // normalized alphas per layer

    const float invD = 1.f / (float)DIM;
    const size_t lstride = (size_t)bt_total * DIM;
    const float* lop = lo + (size_t)bt * DIM + c0;

    // 4-step (16-lane) wave reduce, group leader writes LDS
    auto wred = [&](float x, int slot) {
        x += __shfl_xor(x, 1);
        x += __shfl_xor(x, 2);
        x += __shfl_xor(x, 4);
        x += __shfl_xor(x, 8);
        if ((lane & 15) == 0) red[grp][slot] = x;
    };

    // weight slice (only needed when !PREMUL)
    float wv[EPT];
    if (!PREMUL) {
        vf4 w0 = *reinterpret_cast<const vf4*>(wgt + c0);
        wv[0]=w0.x; wv[1]=w0.y; wv[2]=w0.z; wv[3]=w0.w;
    }

    // ---- embedding slice (registers for whole kernel)
    float e[EPT];
    {
        vf4 v0 = __builtin_nontemporal_load(
            reinterpret_cast<const vf4*>(emb + (size_t)bt * DIM + c0));
        e[0]=v0.x; e[1]=v0.y; e[2]=v0.z; e[3]=v0.w;
    }

    unsigned fpk[LAYERS-1][EPT/2];   // f_0..f_22 packed bf16x2 (46 regs)
    unsigned Spk[NBLK-1][EPT/2];     // finished block sums S_0..S_6, bf16x2
    float part[EPT];                 // running within-block partial (f32)

    // ================= PHASE 1: stream, evolve, emit reduction partials ====
    // l = 0: out = emb (softmax over single source), seed part
    {
        vf4 u0 = __builtin_nontemporal_load(reinterpret_cast<const vf4*>(lop));
        part[0]=u0.x; part[1]=u0.y; part[2]=u0.z; part[3]=u0.w;
        fpk[0][0] = pk2(part[0], part[1]);
        fpk[0][1] = pk2(part[2], part[3]);

        vf4 w0; w0.x=e[0]; w0.y=e[1]; w0.z=e[2]; w0.w=e[3];
        *reinterpret_cast<vf4*>(out + (size_t)bt * DIM + c0) = w0;

        float sq = e[0]*e[0] + e[1]*e[1] + e[2]*e[2] + e[3]*e[3];
        wred(sq, 0);
    }

    // ---- 2-deep register double-buffer for f / qw (ping-pong on l&1)
    float fb[2][EPT], qb[2][EPT];
    {   // prefetch layer 1 (slot 1) and layer 2 (slot 0)
        vf4 u1 = __builtin_nontemporal_load(
            reinterpret_cast<const vf4*>(lop + 1 * lstride));
        fb[1][0]=u1.x; fb[1][1]=u1.y; fb[1][2]=u1.z; fb[1][3]=u1.w;
        vf4 q1v = *reinterpret_cast<const vf4*>(q1 + (size_t)1 * DIM + c0);
        qb[1][0]=q1v.x; qb[1][1]=q1v.y; qb[1][2]=q1v.z; qb[1][3]=q1v.w;

        vf4 u2 = __builtin_nontemporal_load(
            reinterpret_cast<const vf4*>(lop + 2 * lstride));
        fb[0][0]=u2.x; fb[0][1]=u2.y; fb[0][2]=u2.z; fb[0][3]=u2.w;
        vf4 q2v = *reinterpret_cast<const vf4*>(q1 + (size_t)2 * DIM + c0);
        qb[0][0]=q2v.x; qb[0][1]=q2v.y; qb[0][2]=q2v.z; qb[0][3]=q2v.w;
    }

    #pragma unroll
    for (int l = 1; l < LAYERS; ++l) {
        const int m   = l / 3;
        const int i   = l - 3 * m;
        const int off = OFF_TAB[l];
        const int p   = l & 1;

        // copy out current buffers (forces the precise vmcnt wait here)
        float qwv[EPT];
        #pragma unroll
        for (int j = 0; j < EPT; ++j)
            qwv[j] = PREMUL ? qb[p][j] : qb[p][j] * wv[j];
        float fC[EPT];
        if (l < LAYERS - 1) {
            #pragma unroll
            for (int j = 0; j < EPT; ++j) fC[j] = fb[p][j];
        }

        // issue layer l+2's loads NOW (in flight during this layer's compute)
        if (l + 2 <= LAYERS - 2) {   // f needed only through layer 22
            vf4 u0 = __builtin_nontemporal_load(
                reinterpret_cast<const vf4*>(lop + (size_t)(l + 2) * lstride));
            fb[p][0]=u0.x; fb[p][1]=u0.y; fb[p][2]=u0.z; fb[p][3]=u0.w;
        }
        if (l + 2 <= LAYERS - 1) {   // qw needed through layer 23
            vf4 v0 = *reinterpret_cast<const vf4*>(q1 + (size_t)(l + 2) * DIM + c0);
            qb[p][0]=v0.x; qb[p][1]=v0.y; qb[p][2]=v0.z; qb[p][3]=v0.w;
        }

        // dot(emb, qw)
        {
            float dv = e[0]*qwv[0] + e[1]*qwv[1] + e[2]*qwv[2] + e[3]*qwv[3];
            wred(dv, off);
        }
        // dot(S_s, qw); at i==0 the newest S (s=m-1) is still in f32 `part`
        #pragma unroll
        for (int s = 0; s < NBLK - 1; ++s) {
            if (s < m) {
                float dv;
                if (s == m - 1 && i == 0) {
                    dv = part[0]*qwv[0] + part[1]*qwv[1]
                       + part[2]*qwv[2] + part[3]*qwv[3];
                } else {
                    dv = upk(Spk[s][0],0)*qwv[0] + upk(Spk[s][0],1)*qwv[1]
                       + upk(Spk[s][1],0)*qwv[2] + upk(Spk[s][1],1)*qwv[3];
                }
                wred(dv, off + 1 + s);
            }
        }
        if (i > 0) {
            float dv = part[0]*qwv[0] + part[1]*qwv[1]
                     + part[2]*qwv[2] + part[3]*qwv[3];
            float sq = part[0]*part[0] + part[1]*part[1]
                     + part[2]*part[2] + part[3]*part[3];
            wred(dv, off + m + 1);
            wred(sq, off + m + 2);
        } else {
            // part still holds S_{m-1} in f32 here
            float sq = part[0]*part[0] + part[1]*part[1]
                     + part[2]*part[2] + part[3]*part[3];
            wred(sq, off + m + 1);
        }

        // advance partial / finalize block sum
        if (l < LAYERS - 1) {
            if (i == 0) {
                #pragma unroll
                for (int j = 0; j < EPT; ++j) part[j] = fC[j];
            } else {
                #pragma unroll
                for (int j = 0; j < EPT; ++j) part[j] += fC[j];
            }
            fpk[l][0] = pk2(fC[0], fC[1]);
            fpk[l][1] = pk2(fC[2], fC[3]);
            if (i == 2 && m < NBLK - 1) {
                Spk[m][0] = pk2(part[0], part[1]);
                Spk[m][1] = pk2(part[2], part[3]);
            }
        }
    }

    __syncthreads();   // barrier 1: all group partials in red[][]

    // ================= PHASE 2a: join 32 group partials per slot ===========
    if (tid < NSLOT) {
        float t = 0.f;
        #pragma unroll
        for (int g = 0; g < 32; ++g) t += red[g][tid];
        redJ[tid] = t;
    }
    __syncthreads();   // barrier 2: joined scalars ready

    // ================= PHASE 2b: per-layer scores + softmax (23 threads) ===
    if (tid >= 1 && tid < LAYERS) {
        const int l = tid;
        const int m = l / 3;
        const int i = l - 3 * m;
        const int off = OFF_TAB[l];
        const float ssqe = redJ[0];
        float sce = redJ[off] * rsqrtf(ssqe * invD + EPSV);
        float mx = sce;
        float scS[NBLK - 1];
        #pragma unroll
        for (int s = 0; s < NBLK - 1; ++s) {
            if (s < m) {
                scS[s] = redJ[off + 1 + s] * rsqrtf(redJ[SSQS[s]] * invD + EPSV);
                mx = fmaxf(mx, scS[s]);
            }
        }
        float scp = 0.f;
        if (i > 0) {
            scp = redJ[off + m + 1] * rsqrtf(redJ[off + m + 2] * invD + EPSV);
            mx = fmaxf(mx, scp);
        }
        float ee = __expf(sce - mx), den = ee;
        float es[NBLK - 1];
        #pragma unroll
        for (int s = 0; s < NBLK - 1; ++s) {
            es[s] = (s < m) ? __expf(scS[s] - mx) : 0.f;
            den += es[s];
        }
        float ep = 0.f;
        if (i > 0) { ep = __expf(scp - mx); den += ep; }
        const float inv = 1.f / den;
        ab[l][0] = ee * inv;
        #pragma unroll
        for (int s = 0; s < NBLK - 1; ++s)
            if (s < m) ab[l][1 + s] = es[s] * inv;
        if (i > 0) ab[l][1 + m] = ep * inv;
    }
    __syncthreads();   // barrier 3: alphas ready

    // ================= PHASE 3: emit outputs (no sync, pure FMA) ===========
    // re-evolve partial from bf16 f's
    part[0] = upk(fpk[0][0],0); part[1] = upk(fpk[0][0],1);
    part[2] = upk(fpk[0][1],0); part[3] = upk(fpk[0][1],1);

    #pragma unroll
    for (int l = 1; l < LAYERS; ++l) {
        const int m = l / 3;
        const int i = l - 3 * m;

        float h[EPT];
        {
            const float a0 = ab[l][0];
            #pragma unroll
            for (int j = 0; j < EPT; ++j) h[j] = a0 * e[j];
        }
        #pragma unroll
        for (int s = 0; s < NBLK - 1; ++s) {
            if (s < m) {
                const float a = ab[l][1 + s];
                h[0] += a * upk(Spk[s][0],0);
                h[1] += a * upk(Spk[s][0],1);
                h[2] += a * upk(Spk[s][1],0);
                h[3] += a * upk(Spk[s][1],1);
            }
        }
        if (i > 0) {
            const float a = ab[l][1 + m];
            #pragma unroll
            for (int j = 0; j < EPT; ++j) h[j] += a * part[j];
        }

        {
            vf4 w0; w0.x=h[0]; w0.y=h[1]; w0.z=h[2]; w0.w=h[3];
            *reinterpret_cast<vf4*>(out + ((size_t)l * bt_total + bt) * DIM + c0) = w0;
        }

        if (l < LAYERS - 1) {
            if (i == 0) {
                part[0] = upk(fpk[l][0],0); part[1] = upk(fpk[l][0],1);
                part[2] = upk(fpk[l][1],0); part[3] = upk(fpk[l][1],1);
            } else {
                part[0] += upk(fpk[l][0],0); part[1] += upk(fpk[l][0],1);
                part[2] += upk(fpk[l][1],0); part[3] += upk(fpk[l][1],1);
            }
        }
    }
}

extern "C" void kernel_launch(void* const* d_in, const int* in_sizes, int n_in,
                              void* d_out, int out_size, void* d_ws, size_t ws_size,
                              hipStream_t stream) {
    const float* lo  = (const float*)d_in[0];  // layer_outputs (L,B,T,D)
    const float* emb = (const float*)d_in[1];  // embedding (B,T,D)
    const float* qry = (const float*)d_in[2];  // queries (L,D)
    const float* wgt = (const float*)d_in[3];  // key_norm_weight (D)
    float* outp = (float*)d_out;

    const int bt_total = in_sizes[1] / DIM;    // B*T
    const int nq = in_sizes[2];                // L*D

    if (ws_size >= (size_t)nq * sizeof(float)) {
        float* qwbuf = (float*)d_ws;
        prep_qw_kernel<<<(nq + 255) / 256, 256, 0, stream>>>(qry, wgt, qwbuf, nq);
        block_attn_res_kernel<true><<<bt_total, TPB, 0, stream>>>(
            lo, emb, qwbuf, nullptr, outp, bt_total);
    } else {
        block_attn_res_kernel<false><<<bt_total, TPB, 0, stream>>>(
            lo, emb, qry, wgt, outp, bt_total);
    }
}